// Round 1
// baseline (821.155 us; speedup 1.0000x reference)
//
#include <hip/hip_runtime.h>
#include <cmath>

#define LOG2E 1.4426950408889634f

constexpr int Bb = 8;
constexpr int Ll = 4096;
constexpr int Mrows = Bb * Ll;      // 32768
constexpr int NC = 128;             // chunks per sequence
constexpr int CL = Ll / NC;         // 32 steps per chunk

// ---------------------------------------------------------------------------
// Token embedding: circular conv, kernel 3, C_IN=9 -> D_MODEL=128
// ---------------------------------------------------------------------------
__global__ __launch_bounds__(128) void k_embed(const float* __restrict__ t,
                                               const float* __restrict__ w,
                                               float* __restrict__ x) {
  __shared__ float ws[128 * 27];
  const int d = threadIdx.x;
  for (int i = d; i < 128 * 27; i += 128) ws[i] = w[i];
  __syncthreads();
  const int bpb = Ll / 32;
  const int b = blockIdx.x / bpb;
  const int l0 = (blockIdx.x % bpb) * 32;
  const float* wd = &ws[d * 27];
  for (int l = l0; l < l0 + 32; ++l) {
    float acc = 0.f;
#pragma unroll
    for (int k = 0; k < 3; ++k) {
      int li = l + k - 1;
      if (li < 0) li += Ll;
      if (li >= Ll) li -= Ll;
      const float* tr = t + ((size_t)b * Ll + li) * 9;
#pragma unroll
      for (int c = 0; c < 9; ++c) acc = fmaf(tr[c], wd[c * 3 + k], acc);
    }
    x[((size_t)b * Ll + l) * 128 + d] = acc;
  }
}

// ---------------------------------------------------------------------------
// Generic fp32 GEMM: C[m][n] = sum_k A[m][k] * W[n][k]
// A: lda-strided row-major, W: N x K row-major, C: ldc-strided row-major.
// grid = (M/BM, ceil(N/BN)), 256 threads. M multiple of BM, K multiple of BK.
// ---------------------------------------------------------------------------
template <int BM, int BN, int BK, int TM, int TN>
__global__ __launch_bounds__(256) void sgemm_tn(const float* __restrict__ A, int lda,
                                                const float* __restrict__ W, int ldw,
                                                float* __restrict__ C, int ldc,
                                                int N, int K) {
  constexpr int TX = BN / TN;
  constexpr int TY = BM / TM;
  static_assert(TX * TY == 256, "bad tile");
  __shared__ float As[BK][BM + 4];
  __shared__ float Bs[BK][BN + 4];
  const int m0 = blockIdx.x * BM;
  const int n0 = blockIdx.y * BN;
  const int tid = threadIdx.x;
  const int tx = tid % TX, ty = tid / TX;
  float acc[TM][TN];
#pragma unroll
  for (int i = 0; i < TM; ++i)
#pragma unroll
    for (int j = 0; j < TN; ++j) acc[i][j] = 0.f;

  constexpr int KV = BK / 4;          // float4 per k-row
  const int lrow = tid / KV;
  const int lcol = (tid % KV) * 4;
  constexpr int RSTEP = 256 / KV;

  for (int k0 = 0; k0 < K; k0 += BK) {
#pragma unroll
    for (int r = lrow; r < BM; r += RSTEP) {
      float4 v = *(const float4*)(A + (size_t)(m0 + r) * lda + k0 + lcol);
      As[lcol + 0][r] = v.x; As[lcol + 1][r] = v.y;
      As[lcol + 2][r] = v.z; As[lcol + 3][r] = v.w;
    }
#pragma unroll
    for (int r = lrow; r < BN; r += RSTEP) {
      float4 v = make_float4(0.f, 0.f, 0.f, 0.f);
      if (n0 + r < N) v = *(const float4*)(W + (size_t)(n0 + r) * ldw + k0 + lcol);
      Bs[lcol + 0][r] = v.x; Bs[lcol + 1][r] = v.y;
      Bs[lcol + 2][r] = v.z; Bs[lcol + 3][r] = v.w;
    }
    __syncthreads();
#pragma unroll
    for (int k = 0; k < BK; ++k) {
      float ra[TM], rb[TN];
#pragma unroll
      for (int i = 0; i < TM; i += 4) {
        float4 v = *(const float4*)&As[k][ty * TM + i];
        ra[i + 0] = v.x; ra[i + 1] = v.y; ra[i + 2] = v.z; ra[i + 3] = v.w;
      }
#pragma unroll
      for (int j = 0; j < TN; j += 4) {
        float4 v = *(const float4*)&Bs[k][tx * TN + j];
        rb[j + 0] = v.x; rb[j + 1] = v.y; rb[j + 2] = v.z; rb[j + 3] = v.w;
      }
#pragma unroll
      for (int i = 0; i < TM; ++i)
#pragma unroll
        for (int j = 0; j < TN; ++j) acc[i][j] = fmaf(ra[i], rb[j], acc[i][j]);
    }
    __syncthreads();
  }
#pragma unroll
  for (int i = 0; i < TM; ++i) {
    const size_t row = (size_t)(m0 + ty * TM + i) * ldc + n0;
#pragma unroll
    for (int j = 0; j < TN; j += 4) {
      const int col = tx * TN + j;
      if (n0 + col < N) {
        float4 v = make_float4(acc[i][j], acc[i][j + 1], acc[i][j + 2], acc[i][j + 3]);
        *(float4*)(C + row + col) = v;
      }
    }
  }
}

// ---------------------------------------------------------------------------
// Depthwise causal conv (k=4) + bias + silu.  xz: (B,L,512), u: (B,L,256)
// ---------------------------------------------------------------------------
__global__ __launch_bounds__(256) void k_conv_silu(const float* __restrict__ xz,
                                                   const float* __restrict__ cw,
                                                   const float* __restrict__ cb,
                                                   float* __restrict__ u) {
  const int idx = blockIdx.x * 256 + threadIdx.x;
  const int d = idx & 255;
  const int bl = idx >> 8;
  const int l = bl & (Ll - 1);
  const float4 wv = *(const float4*)(cw + d * 4);
  float acc = 0.f;
  if (l >= 3) {
    acc = fmaf(xz[((size_t)(bl - 3)) * 512 + d], wv.x, acc);
    acc = fmaf(xz[((size_t)(bl - 2)) * 512 + d], wv.y, acc);
    acc = fmaf(xz[((size_t)(bl - 1)) * 512 + d], wv.z, acc);
    acc = fmaf(xz[((size_t)(bl - 0)) * 512 + d], wv.w, acc);
  } else {
    if (l >= 3) acc = fmaf(xz[((size_t)(bl - 3)) * 512 + d], wv.x, acc);
    if (l >= 2) acc = fmaf(xz[((size_t)(bl - 2)) * 512 + d], wv.y, acc);
    if (l >= 1) acc = fmaf(xz[((size_t)(bl - 1)) * 512 + d], wv.z, acc);
    acc = fmaf(xz[((size_t)bl) * 512 + d], wv.w, acc);
  }
  acc += cb[d];
  const float sig = 1.f / (1.f + expf(-acc));
  u[idx] = acc * sig;
}

// ---------------------------------------------------------------------------
// Selective scan, chunked.  dt recomputed in-register from dbl (r<8) each phase.
// ---------------------------------------------------------------------------
__device__ __forceinline__ float softplus_f(float x) {
  return fmaxf(x, 0.f) + log1pf(expf(-fabsf(x)));
}

__global__ __launch_bounds__(256) void k_scan_ph1(
    const float* __restrict__ u, const float* __restrict__ dbl,
    const float* __restrict__ dtw, const float* __restrict__ dtb,
    const float* __restrict__ alog, float* __restrict__ hloc,
    float* __restrict__ sdtc) {
  const int b = blockIdx.x / NC;
  const int c = blockIdx.x % NC;
  const int d = threadIdx.x;
  float A2[16];
#pragma unroll
  for (int s = 0; s < 16; ++s) A2[s] = -expf(alog[d * 16 + s]) * LOG2E;
  float w8[8];
  {
    float4 a = *(const float4*)(dtw + d * 8);
    float4 bq = *(const float4*)(dtw + d * 8 + 4);
    w8[0] = a.x; w8[1] = a.y; w8[2] = a.z; w8[3] = a.w;
    w8[4] = bq.x; w8[5] = bq.y; w8[6] = bq.z; w8[7] = bq.w;
  }
  const float dtbv = dtb[d];
  float h[16];
#pragma unroll
  for (int s = 0; s < 16; ++s) h[s] = 0.f;
  float sdt = 0.f;
  const float* ub = u + (size_t)b * Ll * 256 + d;
  const float* db = dbl + (size_t)b * Ll * 40;
  const int l0 = c * CL;
  for (int l = l0; l < l0 + CL; ++l) {
    const float uv = ub[(size_t)l * 256];
    const float4 q0 = *(const float4*)(db + (size_t)l * 40);
    const float4 q1 = *(const float4*)(db + (size_t)l * 40 + 4);
    float Bf[16];
#pragma unroll
    for (int i = 0; i < 4; ++i) {
      float4 v = *(const float4*)(db + (size_t)l * 40 + 8 + i * 4);
      Bf[i * 4 + 0] = v.x; Bf[i * 4 + 1] = v.y; Bf[i * 4 + 2] = v.z; Bf[i * 4 + 3] = v.w;
    }
    float dtr = 0.f;
    dtr = fmaf(q0.x, w8[0], dtr); dtr = fmaf(q0.y, w8[1], dtr);
    dtr = fmaf(q0.z, w8[2], dtr); dtr = fmaf(q0.w, w8[3], dtr);
    dtr = fmaf(q1.x, w8[4], dtr); dtr = fmaf(q1.y, w8[5], dtr);
    dtr = fmaf(q1.z, w8[6], dtr); dtr = fmaf(q1.w, w8[7], dtr);
    dtr += dtbv;
    const float sp = softplus_f(dtr);
    sdt += sp;
    const float dtu = sp * uv;
#pragma unroll
    for (int s = 0; s < 16; ++s) {
      const float dA = exp2f(sp * A2[s]);
      h[s] = fmaf(dA, h[s], dtu * Bf[s]);
    }
  }
  const size_t o = (size_t)(b * NC + c) * 256 + d;
#pragma unroll
  for (int i = 0; i < 4; ++i) {
    float4 v = make_float4(h[i * 4], h[i * 4 + 1], h[i * 4 + 2], h[i * 4 + 3]);
    *(float4*)(hloc + o * 16 + i * 4) = v;
  }
  sdtc[o] = sdt;
}

// thread = (b, d, s); sequential over chunks.  grid = B*16 blocks of 256.
__global__ __launch_bounds__(256) void k_scan_ph2(
    const float* __restrict__ alog, const float* __restrict__ hloc,
    const float* __restrict__ sdtc, float* __restrict__ hstart) {
  const int b = blockIdx.x >> 4;
  const int dg = blockIdx.x & 15;
  const int d = dg * 16 + (threadIdx.x >> 4);
  const int s = threadIdx.x & 15;
  const float A2 = -expf(alog[d * 16 + s]) * LOG2E;
  float hs = 0.f;
  for (int c = 0; c < NC; ++c) {
    const size_t o = (size_t)(b * NC + c) * 256 + d;
    hstart[o * 16 + s] = hs;
    const float sdt = sdtc[o];
    hs = fmaf(exp2f(A2 * sdt), hs, hloc[o * 16 + s]);
  }
}

// Re-scan from exact h_start; emit y = (scan_y + u*D) * silu(z) into xz cols 0..255
__global__ __launch_bounds__(256) void k_scan_ph3(
    const float* __restrict__ u, const float* __restrict__ dbl,
    const float* __restrict__ dtw, const float* __restrict__ dtb,
    const float* __restrict__ alog, const float* __restrict__ Dv,
    const float* __restrict__ hstart, float* __restrict__ xz) {
  const int b = blockIdx.x / NC;
  const int c = blockIdx.x % NC;
  const int d = threadIdx.x;
  float A2[16];
#pragma unroll
  for (int s = 0; s < 16; ++s) A2[s] = -expf(alog[d * 16 + s]) * LOG2E;
  float w8[8];
  {
    float4 a = *(const float4*)(dtw + d * 8);
    float4 bq = *(const float4*)(dtw + d * 8 + 4);
    w8[0] = a.x; w8[1] = a.y; w8[2] = a.z; w8[3] = a.w;
    w8[4] = bq.x; w8[5] = bq.y; w8[6] = bq.z; w8[7] = bq.w;
  }
  const float dtbv = dtb[d];
  const float Dd = Dv[d];
  float h[16];
  const size_t o = (size_t)(b * NC + c) * 256 + d;
#pragma unroll
  for (int i = 0; i < 4; ++i) {
    float4 v = *(const float4*)(hstart + o * 16 + i * 4);
    h[i * 4 + 0] = v.x; h[i * 4 + 1] = v.y; h[i * 4 + 2] = v.z; h[i * 4 + 3] = v.w;
  }
  const float* ub = u + (size_t)b * Ll * 256 + d;
  const float* db = dbl + (size_t)b * Ll * 40;
  const int l0 = c * CL;
  for (int l = l0; l < l0 + CL; ++l) {
    const float uv = ub[(size_t)l * 256];
    const float4 q0 = *(const float4*)(db + (size_t)l * 40);
    const float4 q1 = *(const float4*)(db + (size_t)l * 40 + 4);
    float Bf[16], Cf[16];
#pragma unroll
    for (int i = 0; i < 4; ++i) {
      float4 v = *(const float4*)(db + (size_t)l * 40 + 8 + i * 4);
      Bf[i * 4 + 0] = v.x; Bf[i * 4 + 1] = v.y; Bf[i * 4 + 2] = v.z; Bf[i * 4 + 3] = v.w;
      float4 vc = *(const float4*)(db + (size_t)l * 40 + 24 + i * 4);
      Cf[i * 4 + 0] = vc.x; Cf[i * 4 + 1] = vc.y; Cf[i * 4 + 2] = vc.z; Cf[i * 4 + 3] = vc.w;
    }
    float dtr = 0.f;
    dtr = fmaf(q0.x, w8[0], dtr); dtr = fmaf(q0.y, w8[1], dtr);
    dtr = fmaf(q0.z, w8[2], dtr); dtr = fmaf(q0.w, w8[3], dtr);
    dtr = fmaf(q1.x, w8[4], dtr); dtr = fmaf(q1.y, w8[5], dtr);
    dtr = fmaf(q1.z, w8[6], dtr); dtr = fmaf(q1.w, w8[7], dtr);
    dtr += dtbv;
    const float sp = softplus_f(dtr);
    const float dtu = sp * uv;
    float y = 0.f;
#pragma unroll
    for (int s = 0; s < 16; ++s) {
      const float dA = exp2f(sp * A2[s]);
      h[s] = fmaf(dA, h[s], dtu * Bf[s]);
      y = fmaf(h[s], Cf[s], y);
    }
    y = fmaf(uv, Dd, y);
    const size_t row = ((size_t)b * Ll + l) * 512;
    const float zv = xz[row + 256 + d];
    const float sig = 1.f / (1.f + expf(-zv));
    xz[row + d] = y * (zv * sig);
  }
}

// ---------------------------------------------------------------------------
// Mean over L then L2-normalize.  grid = B blocks of 1024 threads.
// ---------------------------------------------------------------------------
__global__ __launch_bounds__(1024) void k_pool_norm(const float* __restrict__ x,
                                                    float* __restrict__ out) {
  const int b = blockIdx.x, t = threadIdx.x;
  const int m = t & 127, seg = t >> 7;   // 8 segments of 512
  const float* xb = x + (size_t)b * Ll * 128 + m;
  float s = 0.f;
  const int l0 = seg * (Ll / 8);
  for (int l = l0; l < l0 + Ll / 8; ++l) s += xb[(size_t)l * 128];
  __shared__ float sh[1024];
  __shared__ float pm[128];
  __shared__ float sq[128];
  sh[t] = s;
  __syncthreads();
  if (t < 128) {
    float p = 0.f;
#pragma unroll
    for (int g = 0; g < 8; ++g) p += sh[t + g * 128];
    p *= (1.f / Ll);
    pm[t] = p;
    sq[t] = p * p;
  }
  __syncthreads();
  for (int wd = 64; wd >= 1; wd >>= 1) {
    if (t < wd) sq[t] += sq[t + wd];
    __syncthreads();
  }
  if (t < 128) out[b * 128 + t] = pm[t] / fmaxf(sqrtf(sq[0]), 1e-12f);
}

// ---------------------------------------------------------------------------
extern "C" void kernel_launch(void* const* d_in, const int* in_sizes, int n_in,
                              void* d_out, int out_size, void* d_ws, size_t ws_size,
                              hipStream_t stream) {
  (void)in_sizes; (void)n_in; (void)out_size; (void)ws_size;
  const float* t    = (const float*)d_in[0];
  const float* embw = (const float*)d_in[1];
  const float* inw  = (const float*)d_in[2];
  const float* cw   = (const float*)d_in[3];
  const float* cb   = (const float*)d_in[4];
  const float* xpw  = (const float*)d_in[5];
  const float* dtw  = (const float*)d_in[6];
  const float* dtb  = (const float*)d_in[7];
  const float* alog = (const float*)d_in[8];
  const float* Dv   = (const float*)d_in[9];
  const float* ow   = (const float*)d_in[10];

  float* wsf  = (float*)d_ws;
  float* xz   = wsf;                   // (B,L,512)      16777216 f
  float* xb   = xz + 16777216;         // (B,L,128)       4194304 f
  float* ubuf = xb + 4194304;          // (B,L,256)       8388608 f
  float* dblb = ubuf + 8388608;        // (B,L,40)        1310720 f
  float* hloc = dblb + 1310720;        // (B,NC,256,16)   4194304 f
  float* hst  = hloc + 4194304;        // (B,NC,256,16)   4194304 f
  float* sdtc = hst + 4194304;         // (B,NC,256)       262144 f
  float* outp = (float*)d_out;

  k_embed<<<dim3(Bb * (Ll / 32)), dim3(128), 0, stream>>>(t, embw, xb);

  for (int layer = 0; layer < 2; ++layer) {
    const float* inw_l = inw + (size_t)layer * 512 * 128;
    const float* cw_l  = cw + layer * 256 * 4;
    const float* cb_l  = cb + layer * 256;
    const float* xpw_l = xpw + layer * 40 * 256;
    const float* dtw_l = dtw + layer * 256 * 8;
    const float* dtb_l = dtb + layer * 256;
    const float* al_l  = alog + layer * 256 * 16;
    const float* D_l   = Dv + layer * 256;
    const float* ow_l  = ow + layer * 128 * 256;

    // xz = x @ in_w^T   (M=32768, N=512, K=128)
    sgemm_tn<128, 128, 32, 8, 8><<<dim3(Mrows / 128, 4), 256, 0, stream>>>(
        xb, 128, inw_l, 128, xz, 512, 512, 128);
    // u = silu(causal_conv(xc) + cb)
    k_conv_silu<<<dim3(Mrows), 256, 0, stream>>>(xz, cw_l, cb_l, ubuf);
    // dbl = u @ xp_w^T  (N=40, K=256)
    sgemm_tn<128, 64, 32, 8, 4><<<dim3(Mrows / 128, 1), 256, 0, stream>>>(
        ubuf, 256, xpw_l, 256, dblb, 40, 40, 256);
    // chunked selective scan
    k_scan_ph1<<<dim3(Bb * NC), 256, 0, stream>>>(ubuf, dblb, dtw_l, dtb_l, al_l, hloc, sdtc);
    k_scan_ph2<<<dim3(Bb * 16), 256, 0, stream>>>(al_l, hloc, sdtc, hst);
    k_scan_ph3<<<dim3(Bb * NC), 256, 0, stream>>>(ubuf, dblb, dtw_l, dtb_l, al_l, D_l, hst, xz);
    // x = y @ ow^T  (N=128, K=256), y lives in xz cols 0..255 (lda=512)
    sgemm_tn<128, 128, 32, 8, 8><<<dim3(Mrows / 128, 1), 256, 0, stream>>>(
        xz, 512, ow_l, 256, xb, 128, 128, 256);
  }

  k_pool_norm<<<dim3(Bb), 1024, 0, stream>>>(xb, outp);
}

// Round 2
// 660.102 us; speedup vs baseline: 1.2440x; 1.2440x over previous
//
#include <hip/hip_runtime.h>
#include <cmath>

#define LOG2E 1.4426950408889634f

constexpr int Bb = 8;
constexpr int Ll = 4096;
constexpr int Mrows = Bb * Ll;      // 32768
constexpr int NC = 128;             // chunks per sequence
constexpr int CL = Ll / NC;         // 32 steps per chunk

// ---------------------------------------------------------------------------
// Token embedding: circular conv, kernel 3, C_IN=9 -> D_MODEL=128
// ---------------------------------------------------------------------------
__global__ __launch_bounds__(128) void k_embed(const float* __restrict__ t,
                                               const float* __restrict__ w,
                                               float* __restrict__ x) {
  __shared__ float ws[128 * 27];
  const int d = threadIdx.x;
  for (int i = d; i < 128 * 27; i += 128) ws[i] = w[i];
  __syncthreads();
  const int bpb = Ll / 32;
  const int b = blockIdx.x / bpb;
  const int l0 = (blockIdx.x % bpb) * 32;
  const float* wd = &ws[d * 27];
  for (int l = l0; l < l0 + 32; ++l) {
    float acc = 0.f;
#pragma unroll
    for (int k = 0; k < 3; ++k) {
      int li = l + k - 1;
      if (li < 0) li += Ll;
      if (li >= Ll) li -= Ll;
      const float* tr = t + ((size_t)b * Ll + li) * 9;
#pragma unroll
      for (int c = 0; c < 9; ++c) acc = fmaf(tr[c], wd[c * 3 + k], acc);
    }
    x[((size_t)b * Ll + l) * 128 + d] = acc;
  }
}

// ---------------------------------------------------------------------------
// Generic fp32 GEMM: C[m][n] = sum_k A[m][k] * W[n][k]
// A: lda-strided row-major, W: N x K row-major, C: ldc-strided row-major.
// grid = (M/BM, ceil(N/BN)), 256 threads. M multiple of BM, K multiple of BK.
// ---------------------------------------------------------------------------
template <int BM, int BN, int BK, int TM, int TN>
__global__ __launch_bounds__(256) void sgemm_tn(const float* __restrict__ A, int lda,
                                                const float* __restrict__ W, int ldw,
                                                float* __restrict__ C, int ldc,
                                                int N, int K) {
  constexpr int TX = BN / TN;
  constexpr int TY = BM / TM;
  static_assert(TX * TY == 256, "bad tile");
  __shared__ float As[BK][BM + 4];
  __shared__ float Bs[BK][BN + 4];
  const int m0 = blockIdx.x * BM;
  const int n0 = blockIdx.y * BN;
  const int tid = threadIdx.x;
  const int tx = tid % TX, ty = tid / TX;
  float acc[TM][TN];
#pragma unroll
  for (int i = 0; i < TM; ++i)
#pragma unroll
    for (int j = 0; j < TN; ++j) acc[i][j] = 0.f;

  constexpr int KV = BK / 4;          // float4 per k-row
  const int lrow = tid / KV;
  const int lcol = (tid % KV) * 4;
  constexpr int RSTEP = 256 / KV;

  for (int k0 = 0; k0 < K; k0 += BK) {
#pragma unroll
    for (int r = lrow; r < BM; r += RSTEP) {
      float4 v = *(const float4*)(A + (size_t)(m0 + r) * lda + k0 + lcol);
      As[lcol + 0][r] = v.x; As[lcol + 1][r] = v.y;
      As[lcol + 2][r] = v.z; As[lcol + 3][r] = v.w;
    }
#pragma unroll
    for (int r = lrow; r < BN; r += RSTEP) {
      float4 v = make_float4(0.f, 0.f, 0.f, 0.f);
      if (n0 + r < N) v = *(const float4*)(W + (size_t)(n0 + r) * ldw + k0 + lcol);
      Bs[lcol + 0][r] = v.x; Bs[lcol + 1][r] = v.y;
      Bs[lcol + 2][r] = v.z; Bs[lcol + 3][r] = v.w;
    }
    __syncthreads();
#pragma unroll
    for (int k = 0; k < BK; ++k) {
      float ra[TM], rb[TN];
#pragma unroll
      for (int i = 0; i < TM; i += 4) {
        float4 v = *(const float4*)&As[k][ty * TM + i];
        ra[i + 0] = v.x; ra[i + 1] = v.y; ra[i + 2] = v.z; ra[i + 3] = v.w;
      }
#pragma unroll
      for (int j = 0; j < TN; j += 4) {
        float4 v = *(const float4*)&Bs[k][tx * TN + j];
        rb[j + 0] = v.x; rb[j + 1] = v.y; rb[j + 2] = v.z; rb[j + 3] = v.w;
      }
#pragma unroll
      for (int i = 0; i < TM; ++i)
#pragma unroll
        for (int j = 0; j < TN; ++j) acc[i][j] = fmaf(ra[i], rb[j], acc[i][j]);
    }
    __syncthreads();
  }
#pragma unroll
  for (int i = 0; i < TM; ++i) {
    const size_t row = (size_t)(m0 + ty * TM + i) * ldc + n0;
#pragma unroll
    for (int j = 0; j < TN; j += 4) {
      const int col = tx * TN + j;
      if (n0 + col < N) {
        float4 v = make_float4(acc[i][j], acc[i][j + 1], acc[i][j + 2], acc[i][j + 3]);
        *(float4*)(C + row + col) = v;
      }
    }
  }
}

// ---------------------------------------------------------------------------
// Depthwise causal conv (k=4) + bias + silu.  xz: (B,L,512), u: (B,L,256)
// ---------------------------------------------------------------------------
__global__ __launch_bounds__(256) void k_conv_silu(const float* __restrict__ xz,
                                                   const float* __restrict__ cw,
                                                   const float* __restrict__ cb,
                                                   float* __restrict__ u) {
  const int idx = blockIdx.x * 256 + threadIdx.x;
  const int d = idx & 255;
  const int bl = idx >> 8;
  const int l = bl & (Ll - 1);
  const float4 wv = *(const float4*)(cw + d * 4);
  float acc = 0.f;
  if (l >= 3) {
    acc = fmaf(xz[((size_t)(bl - 3)) * 512 + d], wv.x, acc);
    acc = fmaf(xz[((size_t)(bl - 2)) * 512 + d], wv.y, acc);
    acc = fmaf(xz[((size_t)(bl - 1)) * 512 + d], wv.z, acc);
    acc = fmaf(xz[((size_t)(bl - 0)) * 512 + d], wv.w, acc);
  } else {
    if (l >= 3) acc = fmaf(xz[((size_t)(bl - 3)) * 512 + d], wv.x, acc);
    if (l >= 2) acc = fmaf(xz[((size_t)(bl - 2)) * 512 + d], wv.y, acc);
    if (l >= 1) acc = fmaf(xz[((size_t)(bl - 1)) * 512 + d], wv.z, acc);
    acc = fmaf(xz[((size_t)bl) * 512 + d], wv.w, acc);
  }
  acc += cb[d];
  const float sig = 1.f / (1.f + expf(-acc));
  u[idx] = acc * sig;
}

// ---------------------------------------------------------------------------
// Selective scan, chunked.  dt recomputed in-register from dbl (r<8) each phase.
// ---------------------------------------------------------------------------
__device__ __forceinline__ float softplus_f(float x) {
  return fmaxf(x, 0.f) + log1pf(expf(-fabsf(x)));
}

__global__ __launch_bounds__(256) void k_scan_ph1(
    const float* __restrict__ u, const float* __restrict__ dbl,
    const float* __restrict__ dtw, const float* __restrict__ dtb,
    const float* __restrict__ alog, float* __restrict__ hloc,
    float* __restrict__ sdtc) {
  const int b = blockIdx.x / NC;
  const int c = blockIdx.x % NC;
  const int d = threadIdx.x;
  float A2[16];
#pragma unroll
  for (int s = 0; s < 16; ++s) A2[s] = -expf(alog[d * 16 + s]) * LOG2E;
  float w8[8];
  {
    float4 a = *(const float4*)(dtw + d * 8);
    float4 bq = *(const float4*)(dtw + d * 8 + 4);
    w8[0] = a.x; w8[1] = a.y; w8[2] = a.z; w8[3] = a.w;
    w8[4] = bq.x; w8[5] = bq.y; w8[6] = bq.z; w8[7] = bq.w;
  }
  const float dtbv = dtb[d];
  float h[16];
#pragma unroll
  for (int s = 0; s < 16; ++s) h[s] = 0.f;
  float sdt = 0.f;
  const float* ub = u + (size_t)b * Ll * 256 + d;
  const float* db = dbl + (size_t)b * Ll * 40;
  const int l0 = c * CL;
  for (int l = l0; l < l0 + CL; ++l) {
    const float uv = ub[(size_t)l * 256];
    const float4 q0 = *(const float4*)(db + (size_t)l * 40);
    const float4 q1 = *(const float4*)(db + (size_t)l * 40 + 4);
    float Bf[16];
#pragma unroll
    for (int i = 0; i < 4; ++i) {
      float4 v = *(const float4*)(db + (size_t)l * 40 + 8 + i * 4);
      Bf[i * 4 + 0] = v.x; Bf[i * 4 + 1] = v.y; Bf[i * 4 + 2] = v.z; Bf[i * 4 + 3] = v.w;
    }
    float dtr = 0.f;
    dtr = fmaf(q0.x, w8[0], dtr); dtr = fmaf(q0.y, w8[1], dtr);
    dtr = fmaf(q0.z, w8[2], dtr); dtr = fmaf(q0.w, w8[3], dtr);
    dtr = fmaf(q1.x, w8[4], dtr); dtr = fmaf(q1.y, w8[5], dtr);
    dtr = fmaf(q1.z, w8[6], dtr); dtr = fmaf(q1.w, w8[7], dtr);
    dtr += dtbv;
    const float sp = softplus_f(dtr);
    sdt += sp;
    const float dtu = sp * uv;
#pragma unroll
    for (int s = 0; s < 16; ++s) {
      const float dA = exp2f(sp * A2[s]);
      h[s] = fmaf(dA, h[s], dtu * Bf[s]);
    }
  }
  const size_t o = (size_t)(b * NC + c) * 256 + d;
#pragma unroll
  for (int i = 0; i < 4; ++i) {
    float4 v = make_float4(h[i * 4], h[i * 4 + 1], h[i * 4 + 2], h[i * 4 + 3]);
    *(float4*)(hloc + o * 16 + i * 4) = v;
  }
  sdtc[o] = sdt;
}

// thread = (b, d, s); sequential over chunks.  grid = B*16 blocks of 256.
__global__ __launch_bounds__(256) void k_scan_ph2(
    const float* __restrict__ alog, const float* __restrict__ hloc,
    const float* __restrict__ sdtc, float* __restrict__ hstart) {
  const int b = blockIdx.x >> 4;
  const int dg = blockIdx.x & 15;
  const int d = dg * 16 + (threadIdx.x >> 4);
  const int s = threadIdx.x & 15;
  const float A2 = -expf(alog[d * 16 + s]) * LOG2E;
  float hs = 0.f;
  for (int c = 0; c < NC; ++c) {
    const size_t o = (size_t)(b * NC + c) * 256 + d;
    hstart[o * 16 + s] = hs;
    const float sdt = sdtc[o];
    hs = fmaf(exp2f(A2 * sdt), hs, hloc[o * 16 + s]);
  }
}

// Re-scan from exact h_start; emit y = (scan_y + u*D) * silu(z) into xz cols 0..255
__global__ __launch_bounds__(256) void k_scan_ph3(
    const float* __restrict__ u, const float* __restrict__ dbl,
    const float* __restrict__ dtw, const float* __restrict__ dtb,
    const float* __restrict__ alog, const float* __restrict__ Dv,
    const float* __restrict__ hstart, float* __restrict__ xz) {
  const int b = blockIdx.x / NC;
  const int c = blockIdx.x % NC;
  const int d = threadIdx.x;
  float A2[16];
#pragma unroll
  for (int s = 0; s < 16; ++s) A2[s] = -expf(alog[d * 16 + s]) * LOG2E;
  float w8[8];
  {
    float4 a = *(const float4*)(dtw + d * 8);
    float4 bq = *(const float4*)(dtw + d * 8 + 4);
    w8[0] = a.x; w8[1] = a.y; w8[2] = a.z; w8[3] = a.w;
    w8[4] = bq.x; w8[5] = bq.y; w8[6] = bq.z; w8[7] = bq.w;
  }
  const float dtbv = dtb[d];
  const float Dd = Dv[d];
  float h[16];
  const size_t o = (size_t)(b * NC + c) * 256 + d;
#pragma unroll
  for (int i = 0; i < 4; ++i) {
    float4 v = *(const float4*)(hstart + o * 16 + i * 4);
    h[i * 4 + 0] = v.x; h[i * 4 + 1] = v.y; h[i * 4 + 2] = v.z; h[i * 4 + 3] = v.w;
  }
  const float* ub = u + (size_t)b * Ll * 256 + d;
  const float* db = dbl + (size_t)b * Ll * 40;
  const int l0 = c * CL;
  for (int l = l0; l < l0 + CL; ++l) {
    const float uv = ub[(size_t)l * 256];
    const float4 q0 = *(const float4*)(db + (size_t)l * 40);
    const float4 q1 = *(const float4*)(db + (size_t)l * 40 + 4);
    float Bf[16], Cf[16];
#pragma unroll
    for (int i = 0; i < 4; ++i) {
      float4 v = *(const float4*)(db + (size_t)l * 40 + 8 + i * 4);
      Bf[i * 4 + 0] = v.x; Bf[i * 4 + 1] = v.y; Bf[i * 4 + 2] = v.z; Bf[i * 4 + 3] = v.w;
      float4 vc = *(const float4*)(db + (size_t)l * 40 + 24 + i * 4);
      Cf[i * 4 + 0] = vc.x; Cf[i * 4 + 1] = vc.y; Cf[i * 4 + 2] = vc.z; Cf[i * 4 + 3] = vc.w;
    }
    float dtr = 0.f;
    dtr = fmaf(q0.x, w8[0], dtr); dtr = fmaf(q0.y, w8[1], dtr);
    dtr = fmaf(q0.z, w8[2], dtr); dtr = fmaf(q0.w, w8[3], dtr);
    dtr = fmaf(q1.x, w8[4], dtr); dtr = fmaf(q1.y, w8[5], dtr);
    dtr = fmaf(q1.z, w8[6], dtr); dtr = fmaf(q1.w, w8[7], dtr);
    dtr += dtbv;
    const float sp = softplus_f(dtr);
    const float dtu = sp * uv;
    float y = 0.f;
#pragma unroll
    for (int s = 0; s < 16; ++s) {
      const float dA = exp2f(sp * A2[s]);
      h[s] = fmaf(dA, h[s], dtu * Bf[s]);
      y = fmaf(h[s], Cf[s], y);
    }
    y = fmaf(uv, Dd, y);
    const size_t row = ((size_t)b * Ll + l) * 512;
    const float zv = xz[row + 256 + d];
    const float sig = 1.f / (1.f + expf(-zv));
    xz[row + d] = y * (zv * sig);
  }
}

// ---------------------------------------------------------------------------
// Pooling, two-stage.  Stage 1: grid (B*32) blocks x 128 thr, each block sums
// a 128-step L-chunk -> partial[b*32+c][128].  Stage 2: B blocks x 128 thr.
// ---------------------------------------------------------------------------
__global__ __launch_bounds__(128) void k_pool_part(const float* __restrict__ x,
                                                   float* __restrict__ part) {
  const int b = blockIdx.x >> 5;
  const int c = blockIdx.x & 31;
  const int m = threadIdx.x;
  const float* xb = x + (size_t)b * Ll * 128 + (size_t)c * 128 * 128 + m;
  float s = 0.f;
#pragma unroll 4
  for (int l = 0; l < 128; ++l) s += xb[(size_t)l * 128];
  part[(size_t)blockIdx.x * 128 + m] = s;
}

__global__ __launch_bounds__(128) void k_pool_fin(const float* __restrict__ part,
                                                  float* __restrict__ out) {
  const int b = blockIdx.x, m = threadIdx.x;
  float p = 0.f;
#pragma unroll
  for (int c = 0; c < 32; ++c) p += part[((size_t)b * 32 + c) * 128 + m];
  p *= (1.f / Ll);
  __shared__ float pm[128];
  __shared__ float sq[128];
  pm[m] = p;
  sq[m] = p * p;
  __syncthreads();
  for (int wd = 64; wd >= 1; wd >>= 1) {
    if (m < wd) sq[m] += sq[m + wd];
    __syncthreads();
  }
  out[b * 128 + m] = pm[m] / fmaxf(sqrtf(sq[0]), 1e-12f);
}

// ---------------------------------------------------------------------------
extern "C" void kernel_launch(void* const* d_in, const int* in_sizes, int n_in,
                              void* d_out, int out_size, void* d_ws, size_t ws_size,
                              hipStream_t stream) {
  (void)in_sizes; (void)n_in; (void)out_size; (void)ws_size;
  const float* t    = (const float*)d_in[0];
  const float* embw = (const float*)d_in[1];
  const float* inw  = (const float*)d_in[2];
  const float* cw   = (const float*)d_in[3];
  const float* cb   = (const float*)d_in[4];
  const float* xpw  = (const float*)d_in[5];
  const float* dtw  = (const float*)d_in[6];
  const float* dtb  = (const float*)d_in[7];
  const float* alog = (const float*)d_in[8];
  const float* Dv   = (const float*)d_in[9];
  const float* ow   = (const float*)d_in[10];

  float* wsf  = (float*)d_ws;
  float* xz   = wsf;                   // (B,L,512)      16777216 f
  float* xb   = xz + 16777216;         // (B,L,128)       4194304 f
  float* ubuf = xb + 4194304;          // (B,L,256)       8388608 f
  float* dblb = ubuf + 8388608;        // (B,L,40)        1310720 f
  float* hloc = dblb + 1310720;        // (B,NC,256,16)   4194304 f
  float* hst  = hloc + 4194304;        // (B,NC,256,16)   4194304 f
  float* sdtc = hst + 4194304;         // (B,NC,256)       262144 f
  float* pool = sdtc + 262144;         // (B,32,128)        32768 f
  float* outp = (float*)d_out;

  k_embed<<<dim3(Bb * (Ll / 32)), dim3(128), 0, stream>>>(t, embw, xb);

  for (int layer = 0; layer < 2; ++layer) {
    const float* inw_l = inw + (size_t)layer * 512 * 128;
    const float* cw_l  = cw + layer * 256 * 4;
    const float* cb_l  = cb + layer * 256;
    const float* xpw_l = xpw + layer * 40 * 256;
    const float* dtw_l = dtw + layer * 256 * 8;
    const float* dtb_l = dtb + layer * 256;
    const float* al_l  = alog + layer * 256 * 16;
    const float* D_l   = Dv + layer * 256;
    const float* ow_l  = ow + layer * 128 * 256;

    // xz = x @ in_w^T   (M=32768, N=512, K=128)  grid 1024 blocks
    sgemm_tn<128, 128, 32, 8, 8><<<dim3(Mrows / 128, 4), 256, 0, stream>>>(
        xb, 128, inw_l, 128, xz, 512, 512, 128);
    // u = silu(causal_conv(xc) + cb)
    k_conv_silu<<<dim3(Mrows), 256, 0, stream>>>(xz, cw_l, cb_l, ubuf);
    // dbl = u @ xp_w^T  (N=40, K=256)  BM=64 -> 512 blocks (2/CU)
    sgemm_tn<64, 64, 32, 4, 4><<<dim3(Mrows / 64, 1), 256, 0, stream>>>(
        ubuf, 256, xpw_l, 256, dblb, 40, 40, 256);
    // chunked selective scan
    k_scan_ph1<<<dim3(Bb * NC), 256, 0, stream>>>(ubuf, dblb, dtw_l, dtb_l, al_l, hloc, sdtc);
    k_scan_ph2<<<dim3(Bb * 16), 256, 0, stream>>>(al_l, hloc, sdtc, hst);
    k_scan_ph3<<<dim3(Bb * NC), 256, 0, stream>>>(ubuf, dblb, dtw_l, dtb_l, al_l, D_l, hst, xz);
    // x = y @ ow^T  (N=128, K=256), y in xz cols 0..255.  BM=64 -> 512 blocks
    sgemm_tn<64, 128, 32, 4, 8><<<dim3(Mrows / 64, 1), 256, 0, stream>>>(
        xz, 512, ow_l, 256, xb, 128, 128, 256);
  }

  k_pool_part<<<dim3(Bb * 32), 128, 0, stream>>>(xb, pool);
  k_pool_fin<<<dim3(Bb), 128, 0, stream>>>(pool, outp);
}